// Round 7
// baseline (443.119 us; speedup 1.0000x reference)
//
#include <hip/hip_runtime.h>

// MiniTransformer: B=131072, T=8, D=32, H=64, V=27  (all f32, out f32)
// R13 = R12 resubmitted verbatim (R12 bench was an infra failure:
//   "MI355X container failed twice" — no compile/correctness signal).
// R12: lane-pair row split (2 threads per row, 16 d-channels each).
//   R11 post-mortem (WIN, 243->210us): LDS weights + j-major MLP worked.
//   Remaining stall: VGPR=68 is just over the 64-reg occupancy cliff =>
//   hard cap 4 waves/SIMD, measured ~2.4 resident (30%) => VALU idle >50%.
//   R8 proved the 1-thread-per-row body can't fit 64 regs (o[32]+y[32]
//   alone = 64; forcing it => 5GB scratch). Structural fix: thread pair
//   (2k,2k+1) shares a row, each owns half the channels: o[16],y[16],
//   live ~50 regs => target <=64 VGPR, 8 waves/SIMD. Cross-half reduces
//   (LN sums, MLP h_j, Wout dots) = one __shfl_xor(.,1) each. Pairs
//   always branch together (same t; prefix tail count is even).
//   TELL: VGPR_Count <= 64 or the round's premise failed.

namespace {
constexpr int BTOT = 131072;     // 2^17
constexpr int T = 8;
constexpr int D = 32;
constexpr int H = 64;
constexpr int V = 27;
constexpr int NTOK = 27;
constexpr int NROW = T * NTOK;   // 216
constexpr float EPS = 1e-5f;

// ws layout (float offsets)
constexpr int WS_X  = 0;             // 216*32
constexpr int WS_Q  = 6912;
constexpr int WS_K  = 13824;
constexpr int WS_V  = 20736;
constexpr int WS_SC = 27648;         // 216*216 = 46656
constexpr int NSC   = NROW * NROW;
constexpr int WS_P  = WS_SC + NSC;   // 74304: prefix-output tables
constexpr int NPRE0 = 27;
constexpr int NPRE1 = 729;
constexpr int NPRE2 = 19683;
constexpr int NPRE  = NPRE0 + NPRE1 + NPRE2;   // 20439
constexpr size_t WS_NEED_BIG = (size_t)(WS_P + NPRE * V) * 4;  // ~2.45 MB

// two threads per row now
constexpr int MAIN_BLOCKS = (10 * BTOT) / 256;         // 5120, exact
constexpr int PRE_BLOCKS  = (2 * NPRE + 255) / 256;    // 160
} // namespace

// ---- kernel A: X/Q/K/V row tables, thread per (row,d) ----
__global__ __launch_bounds__(256) void build_rows_kernel(
    const float* __restrict__ tokE, const float* __restrict__ posE,
    const float* __restrict__ Wq, const float* __restrict__ Wk,
    const float* __restrict__ Wv, float* __restrict__ ws) {
  const int idx = blockIdx.x * 256 + threadIdx.x;
  if (idx >= NROW * D) return;
  const int row = idx >> 5, d = idx & 31;
  const int t = row / NTOK, tok = row % NTOK;
  float x[D];
#pragma unroll
  for (int g = 0; g < D / 4; ++g) {
    const float4 a = *(const float4*)(tokE + tok * D + 4 * g);
    const float4 c = *(const float4*)(posE + t * D + 4 * g);
    x[4 * g + 0] = a.x + c.x;
    x[4 * g + 1] = a.y + c.y;
    x[4 * g + 2] = a.z + c.z;
    x[4 * g + 3] = a.w + c.w;
  }
  float aq = 0.f, ak = 0.f, av = 0.f;
#pragma unroll
  for (int k = 0; k < D; ++k) {
    const float xv = x[k];
    aq = fmaf(xv, Wq[k * D + d], aq);
    ak = fmaf(xv, Wk[k * D + d], ak);
    av = fmaf(xv, Wv[k * D + d], av);
  }
  ws[WS_X + row * D + d] = x[d];
  ws[WS_Q + row * D + d] = aq;
  ws[WS_K + row * D + d] = ak;
  ws[WS_V + row * D + d] = av;
}

// ---- kernel B: score table SC[(t*27+tokt)*216 + s*27+toks] ----
__global__ __launch_bounds__(256) void build_sc_kernel(float* __restrict__ ws) {
  const int i = blockIdx.x * 256 + threadIdx.x;
  if (i >= NSC) return;
  const int qrow = i / NROW;
  const int j    = i - qrow * NROW;
  const float4* q = (const float4*)(ws + WS_Q + qrow * D);
  const float4* k = (const float4*)(ws + WS_K + j * D);
  float a = 0.f;
#pragma unroll
  for (int g = 0; g < D / 4; ++g) {
    const float4 qa = q[g], ka = k[g];
    a = fmaf(qa.x, ka.x, a);
    a = fmaf(qa.y, ka.y, a);
    a = fmaf(qa.z, ka.z, a);
    a = fmaf(qa.w, ka.w, a);
  }
  ws[WS_SC + i] = a;
}

// pair reduce: lanes 2k and 2k+1 exchange+add (both lanes get the total)
__device__ __forceinline__ float pair_sum(float v) {
  return v + __shfl_xor(v, 1, 64);
}

// ---- half-row computation. Thread owns d in [half*16, half*16+16).
// rowid[s] = s*27 + toks[s]; weights in LDS (W1T/WoT transposed).
__device__ __forceinline__ void compute_row_half(
    const int t, const int half, const int* rowid,
    const float* __restrict__ ws,
    const float* sW1T, const float* sW2, const float* sWoT,
    float* __restrict__ dst) {
  const int qrow = rowid[t];
  const float* SC = ws + WS_SC + qrow * NROW;
  float sc[T];
#pragma unroll
  for (int s = 0; s < T; ++s)
    sc[s] = (s <= t) ? SC[rowid[s]] : -INFINITY;

  const float m01 = fmaxf(sc[0], sc[1]), m23 = fmaxf(sc[2], sc[3]);
  const float m45 = fmaxf(sc[4], sc[5]), m67 = fmaxf(sc[6], sc[7]);
  const float mx = fmaxf(fmaxf(m01, m23), fmaxf(m45, m67));

  // attention: accumulate o (this half's 16 channels), fuse exp into loop
  float o[16];
#pragma unroll
  for (int d = 0; d < 16; ++d) o[d] = 0.f;
  float den = 0.f;
#pragma unroll
  for (int s = 0; s < T; ++s) {
    if (s <= t) {
      const float ps = __expf(sc[s] - mx);
      den += ps;
      const float4* vr = (const float4*)(ws + WS_V + rowid[s] * D + half * 16);
#pragma unroll
      for (int g = 0; g < 4; ++g) {
        const float4 v4 = vr[g];
        o[4 * g + 0] = fmaf(ps, v4.x, o[4 * g + 0]);
        o[4 * g + 1] = fmaf(ps, v4.y, o[4 * g + 1]);
        o[4 * g + 2] = fmaf(ps, v4.z, o[4 * g + 2]);
        o[4 * g + 3] = fmaf(ps, v4.w, o[4 * g + 3]);
      }
    }
  }
  const float inv = 1.f / den;
  {
    const float4* xr = (const float4*)(ws + WS_X + qrow * D + half * 16);
#pragma unroll
    for (int g = 0; g < 4; ++g) {
      const float4 x4 = xr[g];
      o[4 * g + 0] = fmaf(o[4 * g + 0], inv, x4.x);
      o[4 * g + 1] = fmaf(o[4 * g + 1], inv, x4.y);
      o[4 * g + 2] = fmaf(o[4 * g + 2], inv, x4.z);
      o[4 * g + 3] = fmaf(o[4 * g + 3], inv, x4.w);
    }
  }

  // LayerNorm 1 (half-partials + pair_sum)
  {
    float sa = 0.f, sb = 0.f;
#pragma unroll
    for (int d = 0; d < 16; d += 2) { sa += o[d]; sb += o[d + 1]; }
    const float mean = pair_sum(sa + sb) * (1.f / D);
    float qa = 0.f, qb = 0.f;
#pragma unroll
    for (int d = 0; d < 16; d += 2) {
      const float c0 = o[d] - mean, c1 = o[d + 1] - mean;
      qa = fmaf(c0, c0, qa); qb = fmaf(c1, c1, qb);
    }
    const float rr = rsqrtf(pair_sum(qa + qb) * (1.f / D) + EPS);
#pragma unroll
    for (int d = 0; d < 16; ++d) o[d] = (o[d] - mean) * rr;
  }

  // MLP j-major: h_j = pair_sum(dot(o_half, W1T[j][half])), relu,
  // y_half += h_j * W2[j][half]. No h array; <=2 quads in flight.
  float y[16];
#pragma unroll
  for (int d = 0; d < 16; ++d) y[d] = 0.f;
#pragma unroll
  for (int j = 0; j < H; ++j) {
    const float4* w1r = (const float4*)(sW1T + j * D + half * 16);
    float a0 = 0.f, a1 = 0.f, a2 = 0.f, a3 = 0.f;
#pragma unroll
    for (int g = 0; g < 4; ++g) {
      const float4 w = w1r[g];
      a0 = fmaf(o[4 * g + 0], w.x, a0);
      a1 = fmaf(o[4 * g + 1], w.y, a1);
      a2 = fmaf(o[4 * g + 2], w.z, a2);
      a3 = fmaf(o[4 * g + 3], w.w, a3);
    }
    const float hj = fmaxf(pair_sum((a0 + a1) + (a2 + a3)), 0.f);
    const float4* w2r = (const float4*)(sW2 + j * D + half * 16);
#pragma unroll
    for (int g = 0; g < 4; ++g) {
      const float4 w = w2r[g];
      y[4 * g + 0] = fmaf(hj, w.x, y[4 * g + 0]);
      y[4 * g + 1] = fmaf(hj, w.y, y[4 * g + 1]);
      y[4 * g + 2] = fmaf(hj, w.z, y[4 * g + 2]);
      y[4 * g + 3] = fmaf(hj, w.w, y[4 * g + 3]);
    }
  }

  // residual + LayerNorm 2
#pragma unroll
  for (int d = 0; d < 16; ++d) y[d] += o[d];
  {
    float sa = 0.f, sb = 0.f;
#pragma unroll
    for (int d = 0; d < 16; d += 2) { sa += y[d]; sb += y[d + 1]; }
    const float mean = pair_sum(sa + sb) * (1.f / D);
    float qa = 0.f, qb = 0.f;
#pragma unroll
    for (int d = 0; d < 16; d += 2) {
      const float c0 = y[d] - mean, c1 = y[d + 1] - mean;
      qa = fmaf(c0, c0, qa); qb = fmaf(c1, c1, qb);
    }
    const float rr = rsqrtf(pair_sum(qa + qb) * (1.f / D) + EPS);
#pragma unroll
    for (int d = 0; d < 16; ++d) y[d] = (y[d] - mean) * rr;
  }

  // output projection: both lanes compute each total; split the stores
  // (half 0 -> v 0..13, half 1 -> v 14..26)
#pragma unroll
  for (int v = 0; v < V; ++v) {
    const float4* wr = (const float4*)(sWoT + v * D + half * 16);
    float a0 = 0.f, a1 = 0.f, a2 = 0.f, a3 = 0.f;
#pragma unroll
    for (int g = 0; g < 4; ++g) {
      const float4 w = wr[g];
      a0 = fmaf(y[4 * g + 0], w.x, a0);
      a1 = fmaf(y[4 * g + 1], w.y, a1);
      a2 = fmaf(y[4 * g + 2], w.z, a2);
      a3 = fmaf(y[4 * g + 3], w.w, a3);
    }
    const float tot = pair_sum((a0 + a1) + (a2 + a3));
    if ((v < 14) == (half == 0)) dst[v] = tot;
  }
}

// ---- weight staging into LDS (W1 and Wout transposed) ----
__device__ __forceinline__ void stage_weights(
    const float* __restrict__ W1, const float* __restrict__ W2,
    const float* __restrict__ Wo,
    float* sW1T, float* sW2, float* sWoT) {
  const int tid = threadIdx.x;
  for (int i = tid; i < D * H; i += 256) {
    const int j = i >> 5, d = i & 31;           // i = j*32 + d
    sW1T[i] = W1[d * H + j];
  }
#pragma unroll
  for (int i = tid; i < (H * D) / 4; i += 256)
    ((float4*)sW2)[i] = ((const float4*)W2)[i];
  for (int i = tid; i < V * D; i += 256) {
    const int v = i >> 5, d = i & 31;           // i = v*32 + d
    sWoT[i] = Wo[d * V + v];
  }
  __syncthreads();
}

// ---- kernel C: fused main (t in [3,8), pair-per-row) + prefix build ----
__global__ __launch_bounds__(256) void fused_main_kernel(
    const int* __restrict__ tokens,
    float* __restrict__ ws,
    const float* __restrict__ W1, const float* __restrict__ W2,
    const float* __restrict__ Wo, float* __restrict__ out) {
  __shared__ float sW1T[H * D];   // 8 KB, transposed
  __shared__ float sW2[H * D];    // 8 KB
  __shared__ float sWoT[V * D];   // 3.4 KB, transposed
  stage_weights(W1, W2, Wo, sW1T, sW2, sWoT);

  if (blockIdx.x < MAIN_BLOCKS) {
    const int gid = blockIdx.x * 256 + threadIdx.x;   // [0, 10*BTOT), exact
    const int row = gid >> 1;                         // [0, 5*BTOT)
    const int half = gid & 1;
    const int t = 3 + (row >> 17);                    // block-uniform
    const int b = row & (BTOT - 1);
    const int4 ta = *(const int4*)(tokens + b * T);
    const int4 tb = *(const int4*)(tokens + b * T + 4);
    int rowid[T];
    rowid[0] = ta.x;       rowid[1] = 27 + ta.y;
    rowid[2] = 54 + ta.z;  rowid[3] = 81 + ta.w;
    rowid[4] = 108 + tb.x; rowid[5] = 135 + tb.y;
    rowid[6] = 162 + tb.z; rowid[7] = 189 + tb.w;
    compute_row_half(t, half, rowid, ws, sW1T, sW2, sWoT,
                     out + (long long)(b * T + t) * V);
  } else {
    const int g2 = (blockIdx.x - MAIN_BLOCKS) * 256 + threadIdx.x;
    const int i = g2 >> 1;              // prefix row index
    const int half = g2 & 1;
    if (i >= NPRE) return;              // 2*NPRE is even: pairs exit together
    int t, p;
    if (i < NPRE0)              { t = 0; p = i; }
    else if (i < NPRE0 + NPRE1) { t = 1; p = i - NPRE0; }
    else                        { t = 2; p = i - NPRE0 - NPRE1; }
    int toks0 = 0, toks1 = 0, toks2 = 0;
    if (t == 0) { toks0 = p; }
    else if (t == 1) { toks0 = p / 27; toks1 = p % 27; }
    else { toks0 = p / 729; const int r = p % 729; toks1 = r / 27; toks2 = r % 27; }
    int rowid[T];
    rowid[0] = toks0; rowid[1] = 27 + toks1; rowid[2] = 54 + toks2;
    rowid[3] = 81; rowid[4] = 108; rowid[5] = 135; rowid[6] = 162; rowid[7] = 189;
    compute_row_half(t, half, rowid, ws, sW1T, sW2, sWoT, ws + WS_P + i * V);
  }
}

// ---- kernel G: gather t<=2 rows; thread per (b, r), r in [0,81):
//      each b's three output rows are one contiguous 324B write run ----
__global__ __launch_bounds__(256) void gather_kernel(
    const int* __restrict__ tokens,
    const float* __restrict__ ws,
    float* __restrict__ out) {
  const int idx = blockIdx.x * 256 + threadIdx.x;   // [0, BTOT*81), exact
  const int b = idx / 81;
  const int r = idx - b * 81;
  const int t = r / 27;
  const int j = r - t * 27;
  const int t0 = tokens[b * T + 0];
  const int t1 = tokens[b * T + 1];
  const int t2 = tokens[b * T + 2];
  const int p01 = t0 * 27 + t1;
  const int pi = (t == 0) ? t0
               : (t == 1) ? (NPRE0 + p01)
                          : (NPRE0 + NPRE1 + p01 * 27 + t2);
  out[(long long)b * (T * V) + r] = ws[WS_P + pi * V + j];
}

// ---- fallback: all rows, pair-per-row ----
__global__ __launch_bounds__(256) void mini_kernel_all(
    const int* __restrict__ tokens,
    const float* __restrict__ ws,
    const float* __restrict__ W1, const float* __restrict__ W2,
    const float* __restrict__ Wo, float* __restrict__ out) {
  __shared__ float sW1T[H * D];
  __shared__ float sW2[H * D];
  __shared__ float sWoT[V * D];
  stage_weights(W1, W2, Wo, sW1T, sW2, sWoT);

  const int gid = blockIdx.x * 256 + threadIdx.x;   // [0, 2*BTOT*T)
  const int r = gid >> 1;
  const int half = gid & 1;
  const int b = r >> 3;
  const int t = r & 7;
  const int4 ta = *(const int4*)(tokens + b * T);
  const int4 tb = *(const int4*)(tokens + b * T + 4);
  int rowid[T];
  rowid[0] = ta.x;       rowid[1] = 27 + ta.y;
  rowid[2] = 54 + ta.z;  rowid[3] = 81 + ta.w;
  rowid[4] = 108 + tb.x; rowid[5] = 135 + tb.y;
  rowid[6] = 162 + tb.z; rowid[7] = 189 + tb.w;
  compute_row_half(t, half, rowid, ws, sW1T, sW2, sWoT,
                   out + (long long)r * V);
}

extern "C" void kernel_launch(void* const* d_in, const int* in_sizes, int n_in,
                              void* d_out, int out_size, void* d_ws, size_t ws_size,
                              hipStream_t stream) {
  const int*   tokens  = (const int*)d_in[0];
  const float* tok_emb = (const float*)d_in[1];
  const float* pos_emb = (const float*)d_in[2];
  const float* Wq      = (const float*)d_in[3];
  const float* Wk      = (const float*)d_in[4];
  const float* Wv      = (const float*)d_in[5];
  const float* W1      = (const float*)d_in[6];
  const float* W2      = (const float*)d_in[7];
  const float* Wout    = (const float*)d_in[8];
  float* ws = (float*)d_ws;
  float* out = (float*)d_out;

  hipLaunchKernelGGL(build_rows_kernel, dim3((NROW * D + 255) / 256), dim3(256), 0,
                     stream, tok_emb, pos_emb, Wq, Wk, Wv, ws);
  hipLaunchKernelGGL(build_sc_kernel, dim3((NSC + 255) / 256), dim3(256), 0, stream, ws);

  if (ws_size >= WS_NEED_BIG) {
    hipLaunchKernelGGL(fused_main_kernel, dim3(MAIN_BLOCKS + PRE_BLOCKS), dim3(256), 0,
                       stream, tokens, ws, W1, W2, Wout, out);
    hipLaunchKernelGGL(gather_kernel, dim3((BTOT * 81) / 256), dim3(256), 0, stream,
                       tokens, ws, out);
  } else {
    hipLaunchKernelGGL(mini_kernel_all, dim3((2 * BTOT * T) / 256), dim3(256), 0,
                       stream, tokens, ws, W1, W2, Wout, out);
  }
}

// Round 8
// 260.114 us; speedup vs baseline: 1.7036x; 1.7036x over previous
//
#include <hip/hip_runtime.h>

// MiniTransformer: B=131072, T=8, D=32, H=64, V=27  (f32 in/out)
// R14: R11 structure + f16 packed-math MLP/Wout (v_pk_fma_f16).
//   R12/R13 post-mortem (REJECTED): lane-pair d-split raised VGPR to 92
//   (dup'd softmax + per-j shuffles + both-lanes-Wout); VALU busy-time
//   went UP (102->139us). Reverted to R11 (fused_main 210us, VGPR 68).
//   R11 residual model: wall ~= max(VALU 102us, MLP LDS pipe: 1240
//   broadcast ds_read_b128/row ~ 85-125us/CU) with occupancy capped at
//   4 waves/SIMD by VGPR=68 (>64 cliff).
//   R14 fix: weights + o + y in f16 (h2/h8 ext vectors):
//     - DS instrs halve (8 b128/j vs 16; Wout 4/v vs 8), bytes halve
//     - MLP VALU ~1.8x down (pk_fma = 2 ch/instr)
//     - o,y: 16 regs each (was 32) => target VGPR <= 64 => 8 waves/SIMD
//   f32 kept for: attention gather/softmax, LN mean/var, final store.
//   Error budget: f16 noise (~5e-4 rel) enters post-LN1, damped by
//   Wout (|w|~0.02) => out err ~2-5e-4 << 1.95e-3 tol. TELLS: VGPR<=64;
//   absmax passes.

namespace {
constexpr int BTOT = 131072;     // 2^17
constexpr int T = 8;
constexpr int D = 32;
constexpr int H = 64;
constexpr int V = 27;
constexpr int NTOK = 27;
constexpr int NROW = T * NTOK;   // 216
constexpr float EPS = 1e-5f;

// ws layout (float offsets)
constexpr int WS_X  = 0;             // 216*32
constexpr int WS_Q  = 6912;
constexpr int WS_K  = 13824;
constexpr int WS_V  = 20736;
constexpr int WS_SC = 27648;         // 216*216 = 46656
constexpr int NSC   = NROW * NROW;
constexpr int WS_P  = WS_SC + NSC;   // 74304: prefix-output tables
constexpr int NPRE0 = 27;
constexpr int NPRE1 = 729;
constexpr int NPRE2 = 19683;
constexpr int NPRE  = NPRE0 + NPRE1 + NPRE2;   // 20439
constexpr size_t WS_NEED_BIG = (size_t)(WS_P + NPRE * V) * 4;  // ~2.45 MB

constexpr int MAIN_BLOCKS = (5 * BTOT) / 256;          // 2560, exact
constexpr int PRE_BLOCKS  = (NPRE + 255) / 256;        // 80
} // namespace

typedef _Float16 h2 __attribute__((ext_vector_type(2)));
typedef _Float16 h8 __attribute__((ext_vector_type(8)));   // 16B -> ds_read_b128

#define FMA2(a, b, c) __builtin_elementwise_fma((a), (b), (c))

// acc += w(8 halves) . x(4x h2), 4 parallel chains
__device__ __forceinline__ void dot8(const h8 w, const h2* x,
                                     h2& a0, h2& a1, h2& a2, h2& a3) {
  a0 = FMA2(__builtin_shufflevector(w, w, 0, 1), x[0], a0);
  a1 = FMA2(__builtin_shufflevector(w, w, 2, 3), x[1], a1);
  a2 = FMA2(__builtin_shufflevector(w, w, 4, 5), x[2], a2);
  a3 = FMA2(__builtin_shufflevector(w, w, 6, 7), x[3], a3);
}
// y(4x h2) += hb * w(8 halves)
__device__ __forceinline__ void axpy8(const h2 hb, const h8 w, h2* y) {
  y[0] = FMA2(hb, __builtin_shufflevector(w, w, 0, 1), y[0]);
  y[1] = FMA2(hb, __builtin_shufflevector(w, w, 2, 3), y[1]);
  y[2] = FMA2(hb, __builtin_shufflevector(w, w, 4, 5), y[2]);
  y[3] = FMA2(hb, __builtin_shufflevector(w, w, 6, 7), y[3]);
}

// ---- kernel A: X/Q/K/V row tables, thread per (row,d) ----
__global__ __launch_bounds__(256) void build_rows_kernel(
    const float* __restrict__ tokE, const float* __restrict__ posE,
    const float* __restrict__ Wq, const float* __restrict__ Wk,
    const float* __restrict__ Wv, float* __restrict__ ws) {
  const int idx = blockIdx.x * 256 + threadIdx.x;
  if (idx >= NROW * D) return;
  const int row = idx >> 5, d = idx & 31;
  const int t = row / NTOK, tok = row % NTOK;
  float x[D];
#pragma unroll
  for (int g = 0; g < D / 4; ++g) {
    const float4 a = *(const float4*)(tokE + tok * D + 4 * g);
    const float4 c = *(const float4*)(posE + t * D + 4 * g);
    x[4 * g + 0] = a.x + c.x;
    x[4 * g + 1] = a.y + c.y;
    x[4 * g + 2] = a.z + c.z;
    x[4 * g + 3] = a.w + c.w;
  }
  float aq = 0.f, ak = 0.f, av = 0.f;
#pragma unroll
  for (int k = 0; k < D; ++k) {
    const float xv = x[k];
    aq = fmaf(xv, Wq[k * D + d], aq);
    ak = fmaf(xv, Wk[k * D + d], ak);
    av = fmaf(xv, Wv[k * D + d], av);
  }
  ws[WS_X + row * D + d] = x[d];
  ws[WS_Q + row * D + d] = aq;
  ws[WS_K + row * D + d] = ak;
  ws[WS_V + row * D + d] = av;
}

// ---- kernel B: score table SC[(t*27+tokt)*216 + s*27+toks] ----
__global__ __launch_bounds__(256) void build_sc_kernel(float* __restrict__ ws) {
  const int i = blockIdx.x * 256 + threadIdx.x;
  if (i >= NSC) return;
  const int qrow = i / NROW;
  const int j    = i - qrow * NROW;
  const float4* q = (const float4*)(ws + WS_Q + qrow * D);
  const float4* k = (const float4*)(ws + WS_K + j * D);
  float a = 0.f;
#pragma unroll
  for (int g = 0; g < D / 4; ++g) {
    const float4 qa = q[g], ka = k[g];
    a = fmaf(qa.x, ka.x, a);
    a = fmaf(qa.y, ka.y, a);
    a = fmaf(qa.z, ka.z, a);
    a = fmaf(qa.w, ka.w, a);
  }
  ws[WS_SC + i] = a;
}

// ---- row computation: f32 attention/LN stats, f16 MLP+Wout ----
// sW1T[j]: W1[:,j] (32 halves, 4 h8); sW2[j]: W2[j,:]; sWoT[v]: Wout[:,v]
__device__ __forceinline__ void compute_row(
    const int t, const int* rowid,
    const float* __restrict__ ws,
    const h8* sW1T, const h8* sW2, const h8* sWoT,
    float* __restrict__ dst) {
  const int qrow = rowid[t];
  const float* SC = ws + WS_SC + qrow * NROW;
  float sc[T];
#pragma unroll
  for (int s = 0; s < T; ++s)
    sc[s] = (s <= t) ? SC[rowid[s]] : -INFINITY;

  const float m01 = fmaxf(sc[0], sc[1]), m23 = fmaxf(sc[2], sc[3]);
  const float m45 = fmaxf(sc[4], sc[5]), m67 = fmaxf(sc[6], sc[7]);
  const float mx = fmaxf(fmaxf(m01, m23), fmaxf(m45, m67));

  // attention (f32): o = sum p_s * V[row_s], exp fused into loop
  float o[D];
#pragma unroll
  for (int d = 0; d < D; ++d) o[d] = 0.f;
  float den = 0.f;
#pragma unroll
  for (int s = 0; s < T; ++s) {
    if (s <= t) {
      const float ps = __expf(sc[s] - mx);
      den += ps;
      const float4* vr = (const float4*)(ws + WS_V + rowid[s] * D);
#pragma unroll
      for (int g = 0; g < D / 4; ++g) {
        const float4 v4 = vr[g];
        o[4 * g + 0] = fmaf(ps, v4.x, o[4 * g + 0]);
        o[4 * g + 1] = fmaf(ps, v4.y, o[4 * g + 1]);
        o[4 * g + 2] = fmaf(ps, v4.z, o[4 * g + 2]);
        o[4 * g + 3] = fmaf(ps, v4.w, o[4 * g + 3]);
      }
    }
  }
  const float inv = 1.f / den;
  {
    const float4* xr = (const float4*)(ws + WS_X + qrow * D);
#pragma unroll
    for (int g = 0; g < D / 4; ++g) {
      const float4 x4 = xr[g];
      o[4 * g + 0] = fmaf(o[4 * g + 0], inv, x4.x);
      o[4 * g + 1] = fmaf(o[4 * g + 1], inv, x4.y);
      o[4 * g + 2] = fmaf(o[4 * g + 2], inv, x4.z);
      o[4 * g + 3] = fmaf(o[4 * g + 3], inv, x4.w);
    }
  }

  // LayerNorm 1 (f32 stats), normalize fused into the f16 pack
  h2 o2[16];
  {
    float s1a = 0.f, s1b = 0.f, s1c = 0.f, s1d = 0.f;
#pragma unroll
    for (int d = 0; d < D; d += 4) {
      s1a += o[d]; s1b += o[d + 1]; s1c += o[d + 2]; s1d += o[d + 3];
    }
    const float mean = ((s1a + s1b) + (s1c + s1d)) * (1.f / D);
    float q0 = 0.f, q1 = 0.f, q2 = 0.f, q3 = 0.f;
#pragma unroll
    for (int d = 0; d < D; d += 4) {
      const float c0 = o[d] - mean, c1 = o[d + 1] - mean;
      const float c2 = o[d + 2] - mean, c3 = o[d + 3] - mean;
      q0 = fmaf(c0, c0, q0); q1 = fmaf(c1, c1, q1);
      q2 = fmaf(c2, c2, q2); q3 = fmaf(c3, c3, q3);
    }
    const float rr = rsqrtf(((q0 + q1) + (q2 + q3)) * (1.f / D) + EPS);
#pragma unroll
    for (int k = 0; k < 16; ++k) {
      o2[k] = h2{(_Float16)((o[2 * k] - mean) * rr),
                 (_Float16)((o[2 * k + 1] - mean) * rr)};
    }
  }

  // MLP (f16 packed): h_j = relu(o.W1[:,j]); y += h_j * W2[j,:]
  h2 y2[16];
#pragma unroll
  for (int k = 0; k < 16; ++k) y2[k] = h2{(_Float16)0.f, (_Float16)0.f};
#pragma unroll
  for (int j = 0; j < H; ++j) {
    const h8 wa = sW1T[j * 4 + 0], wb = sW1T[j * 4 + 1];
    const h8 wc = sW1T[j * 4 + 2], wd = sW1T[j * 4 + 3];
    h2 a0 = h2{(_Float16)0.f, (_Float16)0.f};
    h2 a1 = a0, a2 = a0, a3 = a0;
    dot8(wa, &o2[0], a0, a1, a2, a3);
    dot8(wb, &o2[4], a0, a1, a2, a3);
    dot8(wc, &o2[8], a0, a1, a2, a3);
    dot8(wd, &o2[12], a0, a1, a2, a3);
    const h2 hs = (a0 + a1) + (a2 + a3);
    _Float16 hj = (_Float16)(hs[0] + hs[1]);
    hj = (hj > (_Float16)0.f) ? hj : (_Float16)0.f;
    const h2 hb = h2{hj, hj};
    const h8 va = sW2[j * 4 + 0], vb = sW2[j * 4 + 1];
    const h8 vc = sW2[j * 4 + 2], vd = sW2[j * 4 + 3];
    axpy8(hb, va, &y2[0]);
    axpy8(hb, vb, &y2[4]);
    axpy8(hb, vc, &y2[8]);
    axpy8(hb, vd, &y2[12]);
  }

  // residual (f16) + LayerNorm 2 (f32 stats, f16 repack)
#pragma unroll
  for (int k = 0; k < 16; ++k) y2[k] = y2[k] + o2[k];
  {
    float z[D];
#pragma unroll
    for (int k = 0; k < 16; ++k) {
      z[2 * k]     = (float)y2[k][0];
      z[2 * k + 1] = (float)y2[k][1];
    }
    float s1a = 0.f, s1b = 0.f, s1c = 0.f, s1d = 0.f;
#pragma unroll
    for (int d = 0; d < D; d += 4) {
      s1a += z[d]; s1b += z[d + 1]; s1c += z[d + 2]; s1d += z[d + 3];
    }
    const float mean = ((s1a + s1b) + (s1c + s1d)) * (1.f / D);
    float q0 = 0.f, q1 = 0.f, q2 = 0.f, q3 = 0.f;
#pragma unroll
    for (int d = 0; d < D; d += 4) {
      const float c0 = z[d] - mean, c1 = z[d + 1] - mean;
      const float c2 = z[d + 2] - mean, c3 = z[d + 3] - mean;
      q0 = fmaf(c0, c0, q0); q1 = fmaf(c1, c1, q1);
      q2 = fmaf(c2, c2, q2); q3 = fmaf(c3, c3, q3);
    }
    const float rr = rsqrtf(((q0 + q1) + (q2 + q3)) * (1.f / D) + EPS);
#pragma unroll
    for (int k = 0; k < 16; ++k) {
      y2[k] = h2{(_Float16)((z[2 * k] - mean) * rr),
                 (_Float16)((z[2 * k + 1] - mean) * rr)};
    }
  }

  // output projection (f16 packed dot per v, f32 store)
#pragma unroll
  for (int v = 0; v < V; ++v) {
    const h8 wa = sWoT[v * 4 + 0], wb = sWoT[v * 4 + 1];
    const h8 wc = sWoT[v * 4 + 2], wd = sWoT[v * 4 + 3];
    h2 a0 = h2{(_Float16)0.f, (_Float16)0.f};
    h2 a1 = a0, a2 = a0, a3 = a0;
    dot8(wa, &y2[0], a0, a1, a2, a3);
    dot8(wb, &y2[4], a0, a1, a2, a3);
    dot8(wc, &y2[8], a0, a1, a2, a3);
    dot8(wd, &y2[12], a0, a1, a2, a3);
    const h2 s = (a0 + a1) + (a2 + a3);
    dst[v] = (float)(s[0] + s[1]);
  }
}

// ---- weight staging into LDS as f16 (W1, Wout transposed) ----
__device__ __forceinline__ void stage_weights(
    const float* __restrict__ W1, const float* __restrict__ W2,
    const float* __restrict__ Wo,
    h8* sW1T, h8* sW2, h8* sWoT) {
  _Float16* a = (_Float16*)sW1T;
  _Float16* b = (_Float16*)sW2;
  _Float16* c = (_Float16*)sWoT;
  const int tid = threadIdx.x;
  for (int i = tid; i < H * D; i += 256) {
    const int j = i >> 5, d = i & 31;           // i = j*32 + d
    a[i] = (_Float16)W1[d * H + j];             // W1T[j][d]
    b[i] = (_Float16)W2[i];                     // W2[j][d] (identity layout)
  }
  for (int i = tid; i < V * D; i += 256) {
    const int v = i >> 5, d = i & 31;           // i = v*32 + d
    c[i] = (_Float16)Wo[d * V + v];             // WoT[v][d]
  }
  __syncthreads();
}

// ---- kernel C: fused main (t in [3,8), t-major) + prefix-table build ----
__global__ __launch_bounds__(256) void fused_main_kernel(
    const int* __restrict__ tokens,
    float* __restrict__ ws,
    const float* __restrict__ W1, const float* __restrict__ W2,
    const float* __restrict__ Wo, float* __restrict__ out) {
  __shared__ h8 sW1T[H * 4];   // 4 KB
  __shared__ h8 sW2[H * 4];    // 4 KB
  __shared__ h8 sWoT[V * 4];   // 1.7 KB
  stage_weights(W1, W2, Wo, sW1T, sW2, sWoT);

  if (blockIdx.x < MAIN_BLOCKS) {
    const int idx = blockIdx.x * 256 + threadIdx.x;   // [0, 5*BTOT), exact
    const int t = 3 + (idx >> 17);                    // wave-uniform (BTOT=2^17)
    const int b = idx & (BTOT - 1);
    const int4 ta = *(const int4*)(tokens + b * T);
    const int4 tb = *(const int4*)(tokens + b * T + 4);
    int rowid[T];
    rowid[0] = ta.x;       rowid[1] = 27 + ta.y;
    rowid[2] = 54 + ta.z;  rowid[3] = 81 + ta.w;
    rowid[4] = 108 + tb.x; rowid[5] = 135 + tb.y;
    rowid[6] = 162 + tb.z; rowid[7] = 189 + tb.w;
    compute_row(t, rowid, ws, sW1T, sW2, sWoT,
                out + (long long)(b * T + t) * V);
  } else {
    const int i = (blockIdx.x - MAIN_BLOCKS) * 256 + threadIdx.x;
    if (i >= NPRE) return;
    int t, p;
    if (i < NPRE0)              { t = 0; p = i; }
    else if (i < NPRE0 + NPRE1) { t = 1; p = i - NPRE0; }
    else                        { t = 2; p = i - NPRE0 - NPRE1; }
    int toks0 = 0, toks1 = 0, toks2 = 0;
    if (t == 0) { toks0 = p; }
    else if (t == 1) { toks0 = p / 27; toks1 = p % 27; }
    else { toks0 = p / 729; const int r = p % 729; toks1 = r / 27; toks2 = r % 27; }
    int rowid[T];
    rowid[0] = toks0; rowid[1] = 27 + toks1; rowid[2] = 54 + toks2;
    rowid[3] = 81; rowid[4] = 108; rowid[5] = 135; rowid[6] = 162; rowid[7] = 189;
    compute_row(t, rowid, ws, sW1T, sW2, sWoT, ws + WS_P + i * V);
  }
}

// ---- kernel G: gather t<=2 rows; thread per (b, r), r in [0,81):
//      each b's three output rows are one contiguous 324B write run ----
__global__ __launch_bounds__(256) void gather_kernel(
    const int* __restrict__ tokens,
    const float* __restrict__ ws,
    float* __restrict__ out) {
  const int idx = blockIdx.x * 256 + threadIdx.x;   // [0, BTOT*81), exact
  const int b = idx / 81;
  const int r = idx - b * 81;
  const int t = r / 27;
  const int j = r - t * 27;
  const int t0 = tokens[b * T + 0];
  const int t1 = tokens[b * T + 1];
  const int t2 = tokens[b * T + 2];
  const int p01 = t0 * 27 + t1;
  const int pi = (t == 0) ? t0
               : (t == 1) ? (NPRE0 + p01)
                          : (NPRE0 + NPRE1 + p01 * 27 + t2);
  out[(long long)b * (T * V) + r] = ws[WS_P + pi * V + j];
}

// ---- fallback: all rows, thread per row ----
__global__ __launch_bounds__(256) void mini_kernel_all(
    const int* __restrict__ tokens,
    const float* __restrict__ ws,
    const float* __restrict__ W1, const float* __restrict__ W2,
    const float* __restrict__ Wo, float* __restrict__ out) {
  __shared__ h8 sW1T[H * 4];
  __shared__ h8 sW2[H * 4];
  __shared__ h8 sWoT[V * 4];
  stage_weights(W1, W2, Wo, sW1T, sW2, sWoT);

  const int r = blockIdx.x * 256 + threadIdx.x;
  const int b = r >> 3;
  const int t = r & 7;
  const int4 ta = *(const int4*)(tokens + b * T);
  const int4 tb = *(const int4*)(tokens + b * T + 4);
  int rowid[T];
  rowid[0] = ta.x;       rowid[1] = 27 + ta.y;
  rowid[2] = 54 + ta.z;  rowid[3] = 81 + ta.w;
  rowid[4] = 108 + tb.x; rowid[5] = 135 + tb.y;
  rowid[6] = 162 + tb.z; rowid[7] = 189 + tb.w;
  compute_row(t, rowid, ws, sW1T, sW2, sWoT, out + (long long)r * V);
}

extern "C" void kernel_launch(void* const* d_in, const int* in_sizes, int n_in,
                              void* d_out, int out_size, void* d_ws, size_t ws_size,
                              hipStream_t stream) {
  const int*   tokens  = (const int*)d_in[0];
  const float* tok_emb = (const float*)d_in[1];
  const float* pos_emb = (const float*)d_in[2];
  const float* Wq      = (const float*)d_in[3];
  const float* Wk      = (const float*)d_in[4];
  const float* Wv      = (const float*)d_in[5];
  const float* W1      = (const float*)d_in[6];
  const float* W2      = (const float*)d_in[7];
  const float* Wout    = (const float*)d_in[8];
  float* ws = (float*)d_ws;
  float* out = (float*)d_out;

  hipLaunchKernelGGL(build_rows_kernel, dim3((NROW * D + 255) / 256), dim3(256), 0,
                     stream, tok_emb, pos_emb, Wq, Wk, Wv, ws);
  hipLaunchKernelGGL(build_sc_kernel, dim3((NSC + 255) / 256), dim3(256), 0, stream, ws);

  if (ws_size >= WS_NEED_BIG) {
    hipLaunchKernelGGL(fused_main_kernel, dim3(MAIN_BLOCKS + PRE_BLOCKS), dim3(256), 0,
                       stream, tokens, ws, W1, W2, Wout, out);
    hipLaunchKernelGGL(gather_kernel, dim3((BTOT * 81) / 256), dim3(256), 0, stream,
                       tokens, ws, out);
  } else {
    hipLaunchKernelGGL(mini_kernel_all, dim3((BTOT * T) / 256), dim3(256), 0,
                       stream, tokens, ws, W1, W2, Wout, out);
  }
}